// Round 5
// baseline (298.248 us; speedup 1.0000x reference)
//
#include <hip/hip_runtime.h>
#include <cstddef>

// Problem dims (fixed by setup_inputs)
#define Mdim 256     // batch B
#define Ndim 2048    // neurons N
#define Kdim 2048    // K (= N, W is NxN)
#define Tsteps 128   // time steps

// W nonzero bitmap granularity: 16(k) x 128(n) tiles.
// flags byte[c*16 + g]: bit i set iff tile (kt = g*8+i, column c) has a
// nonzero element.  c in [0,16) columns of 128 n; kt in [0,128) k-tiles.

typedef float v4f __attribute__((ext_vector_type(4)));

// ---------------------------------------------------------------------------
// Kernel 1: scan W -> 256-byte tile-nonzero bitmap in ws.
// Grid (16 c, 16 g), 256 threads. Block reads W[g*128:+128, c*128:+128]
// (64 KB) and writes ONE byte (bits = 8 k-tiles of 16 rows). Every byte has
// exactly one writer -> no init, no atomics needed (ws arrives poisoned).
// ---------------------------------------------------------------------------
__global__ __launch_bounds__(256) void scan_w_kernel(
    const float* __restrict__ W, unsigned char* __restrict__ flags)
{
    const int c = blockIdx.x;   // column group (n / 128)
    const int g = blockIdx.y;   // k-tile group (kt / 8)
    const int tid = threadIdx.x;

    __shared__ int wmask[4];

    const int coff = (tid & 31) * 4;       // 0..124
    const int rbase = tid >> 5;            // 0..7

    unsigned mask = 0;
#pragma unroll
    for (int it = 0; it < 16; ++it) {
        const int r = it * 8 + rbase;      // 0..127, tile bit = it>>1
        const float4 v = *(const float4*)&W[(size_t)(g * 128 + r) * Ndim + c * 128 + coff];
        const bool nz = (v.x != 0.0f) | (v.y != 0.0f) | (v.z != 0.0f) | (v.w != 0.0f);
        mask |= (nz ? 1u : 0u) << (it >> 1);
    }
    // wave OR-reduce
#pragma unroll
    for (int off = 32; off; off >>= 1) mask |= __shfl_down(mask, off);
    if ((tid & 63) == 0) wmask[tid >> 6] = (int)mask;
    __syncthreads();
    if (tid == 0) {
        const int m = wmask[0] | wmask[1] | wmask[2] | wmask[3];
        flags[c * 16 + g] = (unsigned char)m;
    }
}

// ---------------------------------------------------------------------------
// Kernel 2: fused current + LIF rollout.
// Block = (b = blockIdx>>1, n-window of 1024). Stages x[b,:] in LDS, then
// each thread computes I for its 4 neurons over FLAGGED k-tiles only
// (skipped tiles contribute exactly +/-0 -> spikes unaffected), then runs
// the 128-step recurrence.
//   V_{t+1} = (ALPHA*V_t + I) * (1 - Z_t);  Z_{t+1} = (V_{t+1} >= 1)
// __fmul_rn/__fadd_rn forbid FMA contraction -> bit-match numpy's mul+add.
// Output (268 MB, write-once) uses nontemporal stores.
// ---------------------------------------------------------------------------
__global__ __launch_bounds__(256) void lif_fused_kernel(
    const float* __restrict__ x, const float* __restrict__ W,
    const unsigned* __restrict__ flags, float* __restrict__ out)
{
    __shared__ float xs[Kdim];   // 8 KB: this block's x row

    const int tid = threadIdx.x;
    const int b = blockIdx.x >> 1;                        // uniform per block
    const int n = ((blockIdx.x & 1) << 10) + tid * 4;     // 0..2047
    const int c = n >> 7;                                 // flag column

    // stage x[b,:] -> LDS (coalesced float4 pairs)
    {
        const float* xp = x + (size_t)b * Kdim;
        *(float4*)&xs[tid * 4]        = *(const float4*)&xp[tid * 4];
        *(float4*)&xs[1024 + tid * 4] = *(const float4*)&xp[1024 + tid * 4];
    }
    __syncthreads();

    // dot over flagged k-tiles, ascending kt (deterministic order)
    float f0 = 0.0f, f1 = 0.0f, f2 = 0.0f, f3 = 0.0f;
#pragma unroll
    for (int w = 0; w < 4; ++w) {
        unsigned word = flags[c * 4 + w];   // bits kt = w*32 + bit
        while (word) {
            const int bit = __builtin_ctz(word);
            word &= word - 1;
            const int k0 = (w * 32 + bit) * 16;
            const float* wp = W + (size_t)k0 * Ndim + n;
#pragma unroll
            for (int kk = 0; kk < 16; ++kk) {
                const float xv = xs[k0 + kk];                    // LDS broadcast
                const float4 wv = *(const float4*)(wp + (size_t)kk * Ndim);
                f0 = fmaf(xv, wv.x, f0);
                f1 = fmaf(xv, wv.y, f1);
                f2 = fmaf(xv, wv.z, f2);
                f3 = fmaf(xv, wv.w, f3);
            }
        }
    }
    const float Iv[4] = {f0, f1, f2, f3};

    // fp32(exp(-0.1) computed in f64) — matches numpy scalar promotion
    const float ALPHA = (float)0.9048374180359595;

    float V[4] = {0.0f, 0.0f, 0.0f, 0.0f};
    float Z[4] = {0.0f, 0.0f, 0.0f, 0.0f};

    float* op = out + (size_t)b * Tsteps * Ndim + n;
#pragma unroll 4
    for (int t = 0; t < Tsteps; ++t) {
#pragma unroll
        for (int j = 0; j < 4; ++j) {
            float v = __fmul_rn(ALPHA, V[j]);          // ALPHA * V
            v = __fadd_rn(v, Iv[j]);                   // + I
            v = __fmul_rn(v, __fsub_rn(1.0f, Z[j]));   // * (1 - Z_prev)
            V[j] = v;
            Z[j] = (v >= 1.0f) ? 1.0f : 0.0f;
        }
        v4f s = {Z[0], Z[1], Z[2], Z[3]};
        __builtin_nontemporal_store(s, (v4f*)&op[(size_t)t * Ndim]);
    }
}

// ---------------------------------------------------------------------------
extern "C" void kernel_launch(void* const* d_in, const int* in_sizes, int n_in,
                              void* d_out, int out_size, void* d_ws, size_t ws_size,
                              hipStream_t stream) {
    const float* x = (const float*)d_in[0];   // [256, 2048] fp32
    const float* W = (const float*)d_in[1];   // [2048, 2048] fp32
    float* out = (float*)d_out;               // [256, 128, 2048] fp32

    unsigned char* flags = (unsigned char*)d_ws;   // 256 bytes used

    scan_w_kernel<<<dim3(16, 16), 256, 0, stream>>>(W, flags);

    const int sim_blocks = Mdim * Ndim / 1024;     // 512
    lif_fused_kernel<<<dim3(sim_blocks), 256, 0, stream>>>(
        x, W, (const unsigned*)flags, out);
}

// Round 6
// 291.977 us; speedup vs baseline: 1.0215x; 1.0215x over previous
//
#include <hip/hip_runtime.h>
#include <cstddef>

// Problem dims (fixed by setup_inputs)
#define Mdim 256     // batch B
#define Ndim 2048    // neurons N
#define Kdim 2048    // K (= N, W is NxN)
#define Tsteps 128   // time steps

typedef float v4f __attribute__((ext_vector_type(4)));

// ---------------------------------------------------------------------------
// Kernel 1: scan W -> 256-byte tile-nonzero bitmap in ws.
// flags byte[c*16 + g]: bit i set iff tile (kt = g*8+i, column c) nonzero.
// Grid (16 c, 16 g), 256 threads; one byte per block, single writer.
// ---------------------------------------------------------------------------
__global__ __launch_bounds__(256) void scan_w_kernel(
    const float* __restrict__ W, unsigned char* __restrict__ flags)
{
    const int c = blockIdx.x;   // column group (n / 128)
    const int g = blockIdx.y;   // k-tile group (kt / 8)
    const int tid = threadIdx.x;

    __shared__ int wmask[4];

    const int coff = (tid & 31) * 4;       // 0..124
    const int rbase = tid >> 5;            // 0..7

    unsigned mask = 0;
#pragma unroll
    for (int it = 0; it < 16; ++it) {
        const int r = it * 8 + rbase;      // 0..127, tile bit = it>>1
        const float4 v = *(const float4*)&W[(size_t)(g * 128 + r) * Ndim + c * 128 + coff];
        const bool nz = (v.x != 0.0f) | (v.y != 0.0f) | (v.z != 0.0f) | (v.w != 0.0f);
        mask |= (nz ? 1u : 0u) << (it >> 1);
    }
#pragma unroll
    for (int off = 32; off; off >>= 1) mask |= __shfl_down(mask, off);
    if ((tid & 63) == 0) wmask[tid >> 6] = (int)mask;
    __syncthreads();
    if (tid == 0) {
        const int m = wmask[0] | wmask[1] | wmask[2] | wmask[3];
        flags[c * 16 + g] = (unsigned char)m;
    }
}

// ---------------------------------------------------------------------------
// Write phase: spikes are pre-packed in zb[j][w] (bit t2 of word w = spike at
// t = w*32+t2). Per-block t-order swizzle (word rotation RW + in-word XOR rx)
// decorrelates concurrent blocks' store addresses across HBM channels while
// covering every t exactly once. Iterations are independent -> deep MLP.
// RW is a template arg so zb word indexing stays static (no scratch).
// ---------------------------------------------------------------------------
template<int RW>
__device__ __forceinline__ void write_spikes(
    const unsigned (&zb)[4][4], float* __restrict__ op, int rx)
{
#pragma unroll
    for (int wi = 0; wi < 4; ++wi) {
        const int w = (wi + RW) & 3;       // compile-time per unrolled wi
#pragma unroll
        for (int t2 = 0; t2 < 32; ++t2) {
            const int t2r = t2 ^ rx;       // bijection on [0,32)
            const int t = w * 32 + t2r;
            v4f s = { (float)((zb[0][w] >> t2r) & 1u),
                      (float)((zb[1][w] >> t2r) & 1u),
                      (float)((zb[2][w] >> t2r) & 1u),
                      (float)((zb[3][w] >> t2r) & 1u) };
            __builtin_nontemporal_store(s, (v4f*)(op + (size_t)t * Ndim));
        }
    }
}

// ---------------------------------------------------------------------------
// Kernel 2: fused current + LIF rollout, store-decoupled.
// Phase A: I[b,n] over flagged W k-tiles (skipped tiles contribute exactly
//          +/-0 -> spikes unaffected; bit-exact for identity-W inputs).
// Phase B: 128-step recurrence, spikes packed into 16 u32 regs (no stores).
//   V_{t+1} = (ALPHA*V_t + I) * (1 - Z_t);  Z_{t+1} = (V_{t+1} >= 1)
//   __fmul_rn/__fadd_rn forbid FMA contraction -> bit-match numpy.
// Phase C: swizzled streaming write of 268 MB (nontemporal).
// ---------------------------------------------------------------------------
__global__ __launch_bounds__(256, 2) void lif_fused_kernel(
    const float* __restrict__ x, const float* __restrict__ W,
    const unsigned* __restrict__ flags, float* __restrict__ out)
{
    __shared__ float xs[Kdim];   // 8 KB: this block's x row

    const int tid = threadIdx.x;
    const int b = blockIdx.x >> 1;                        // uniform per block
    const int n = ((blockIdx.x & 1) << 10) + tid * 4;     // 0..2047
    const int c = n >> 7;                                 // flag column

    // stage x[b,:] -> LDS
    {
        const float* xp = x + (size_t)b * Kdim;
        *(float4*)&xs[tid * 4]        = *(const float4*)&xp[tid * 4];
        *(float4*)&xs[1024 + tid * 4] = *(const float4*)&xp[1024 + tid * 4];
    }
    __syncthreads();

    // ---- Phase A: dot over flagged k-tiles, ascending kt ----
    float f0 = 0.0f, f1 = 0.0f, f2 = 0.0f, f3 = 0.0f;
#pragma unroll
    for (int w = 0; w < 4; ++w) {
        unsigned word = flags[c * 4 + w];   // bits kt = w*32 + bit
        while (word) {
            const int bit = __builtin_ctz(word);
            word &= word - 1;
            const int k0 = (w * 32 + bit) * 16;
            const float* wp = W + (size_t)k0 * Ndim + n;
#pragma unroll
            for (int kk = 0; kk < 16; ++kk) {
                const float xv = xs[k0 + kk];                    // LDS broadcast
                const float4 wv = *(const float4*)(wp + (size_t)kk * Ndim);
                f0 = fmaf(xv, wv.x, f0);
                f1 = fmaf(xv, wv.y, f1);
                f2 = fmaf(xv, wv.z, f2);
                f3 = fmaf(xv, wv.w, f3);
            }
        }
    }
    const float Iv[4] = {f0, f1, f2, f3};

    // fp32(exp(-0.1) computed in f64) — matches numpy scalar promotion
    const float ALPHA = (float)0.9048374180359595;

    // ---- Phase B: recurrence, pack spikes into bits (no stores) ----
    unsigned zb[4][4] = {{0u, 0u, 0u, 0u}, {0u, 0u, 0u, 0u},
                         {0u, 0u, 0u, 0u}, {0u, 0u, 0u, 0u}};
    float V[4] = {0.0f, 0.0f, 0.0f, 0.0f};
    float Z[4] = {0.0f, 0.0f, 0.0f, 0.0f};
#pragma unroll
    for (int w = 0; w < 4; ++w) {
#pragma unroll
        for (int t2 = 0; t2 < 32; ++t2) {
#pragma unroll
            for (int j = 0; j < 4; ++j) {
                float v = __fmul_rn(ALPHA, V[j]);          // ALPHA * V
                v = __fadd_rn(v, Iv[j]);                   // + I
                v = __fmul_rn(v, __fsub_rn(1.0f, Z[j]));   // * (1 - Z_prev)
                V[j] = v;
                const bool sp = (v >= 1.0f);
                Z[j] = sp ? 1.0f : 0.0f;
                zb[j][w] |= sp ? (1u << t2) : 0u;
            }
        }
    }

    // ---- Phase C: swizzled streaming write ----
    float* op = out + (size_t)b * Tsteps * Ndim + n;
    const int rx = (blockIdx.x >> 2) & 31;
    switch (blockIdx.x & 3) {
        case 0: write_spikes<0>(zb, op, rx); break;
        case 1: write_spikes<1>(zb, op, rx); break;
        case 2: write_spikes<2>(zb, op, rx); break;
        default: write_spikes<3>(zb, op, rx); break;
    }
}

// ---------------------------------------------------------------------------
extern "C" void kernel_launch(void* const* d_in, const int* in_sizes, int n_in,
                              void* d_out, int out_size, void* d_ws, size_t ws_size,
                              hipStream_t stream) {
    const float* x = (const float*)d_in[0];   // [256, 2048] fp32
    const float* W = (const float*)d_in[1];   // [2048, 2048] fp32
    float* out = (float*)d_out;               // [256, 128, 2048] fp32

    unsigned char* flags = (unsigned char*)d_ws;   // 256 bytes used

    scan_w_kernel<<<dim3(16, 16), 256, 0, stream>>>(W, flags);

    const int sim_blocks = Mdim * Ndim / 1024;     // 512
    lif_fused_kernel<<<dim3(sim_blocks), 256, 0, stream>>>(
        x, W, (const unsigned*)flags, out);
}